// Round 6
// baseline (2320.332 us; speedup 1.0000x reference)
//
#include <hip/hip_runtime.h>
#include <hip/hip_bf16.h>

using bf16 = __hip_bfloat16;
typedef __attribute__((ext_vector_type(8))) short bf16x8;   // 8 bf16 (4 VGPRs)
typedef __attribute__((ext_vector_type(4))) float f32x4;    // MFMA accumulator

constexpr int NN = 200000;   // nodes
constexpr int NE = 800000;   // edges
constexpr int NG = 4000;     // graphs
constexpr int ED = 16;       // edge feature dim
constexpr float BN_EPS = 1e-5f;

// ---------------- storage-type helpers (fp32 or bf16 node features) --------
__device__ __forceinline__ float  ld1(const float* p) { return *p; }
__device__ __forceinline__ float  ld1(const bf16*  p) { return __bfloat162float(*p); }
__device__ __forceinline__ float2 ld2f(const float* p) { return *(const float2*)p; }
__device__ __forceinline__ float2 ld2f(const bf16*  p) {
    union { ushort2 u; bf16 h[2]; } t;
    t.u = *(const ushort2*)p;
    return make_float2(__bfloat162float(t.h[0]), __bfloat162float(t.h[1]));
}
__device__ __forceinline__ float4 ld4(const float* p) { return *(const float4*)p; }
__device__ __forceinline__ float4 ld4(const bf16*  p) {
    union { ushort4 u; bf16 h[4]; } t;
    t.u = *(const ushort4*)p;
    return make_float4(__bfloat162float(t.h[0]), __bfloat162float(t.h[1]),
                       __bfloat162float(t.h[2]), __bfloat162float(t.h[3]));
}
__device__ __forceinline__ void st1(float* p, float v) { *p = v; }
__device__ __forceinline__ void st1(bf16*  p, float v) { *p = __float2bfloat16(v); }
__device__ __forceinline__ void st4(float* p, float4 v) { *(float4*)p = v; }
__device__ __forceinline__ void st4(bf16*  p, float4 v) {
    union { ushort4 u; bf16 h[4]; } t;
    t.h[0] = __float2bfloat16(v.x); t.h[1] = __float2bfloat16(v.y);
    t.h[2] = __float2bfloat16(v.z); t.h[3] = __float2bfloat16(v.w);
    *(ushort4*)p = t.u;
}

// ===========================================================================
// CSR-by-dst build (once per call; reused by all 3 conv layers)
// ===========================================================================
constexpr int SCAN_CHUNK = 1024;
constexpr int SCAN_NBLK  = (NN + SCAN_CHUNK - 1) / SCAN_CHUNK;   // 196

__global__ __launch_bounds__(256)
void k_hist(const int* __restrict__ ei, int* __restrict__ cnt)
{
    int e = blockIdx.x * 256 + threadIdx.x;
    const int stride = gridDim.x * 256;
    for (; e < NE; e += stride) atomicAdd(&cnt[ei[NE + e]], 1);
}

__global__ __launch_bounds__(256)
void k_scan_block(const int* __restrict__ cnt, int* __restrict__ bsum)
{
    __shared__ int red[256];
    const int b = blockIdx.x, t = threadIdx.x;
    const int base = b * SCAN_CHUNK + t * 4;
    int s = 0;
    #pragma unroll
    for (int k = 0; k < 4; ++k) { const int i = base + k; if (i < NN) s += cnt[i]; }
    red[t] = s; __syncthreads();
    for (int off = 128; off > 0; off >>= 1) {
        if (t < off) red[t] += red[t + off];
        __syncthreads();
    }
    if (t == 0) bsum[b] = red[0];
}

__global__ __launch_bounds__(256)
void k_scan_top(int* __restrict__ bsum, int n)
{
    __shared__ int sh[256];
    const int t = threadIdx.x;
    const int orig = (t < n) ? bsum[t] : 0;
    sh[t] = orig; __syncthreads();
    for (int off = 1; off < 256; off <<= 1) {
        const int v = (t >= off) ? sh[t - off] : 0;
        __syncthreads();
        sh[t] += v;
        __syncthreads();
    }
    if (t < n) bsum[t] = sh[t] - orig;   // exclusive
}

__global__ __launch_bounds__(256)
void k_scan_emit(const int* __restrict__ cnt, const int* __restrict__ bsum,
                 int* __restrict__ row_ptr, int* __restrict__ cursor)
{
    __shared__ int sh[256];
    const int b = blockIdx.x, t = threadIdx.x;
    const int base = b * SCAN_CHUNK + t * 4;
    int c[4]; int s = 0;
    #pragma unroll
    for (int k = 0; k < 4; ++k) {
        const int i = base + k;
        c[k] = (i < NN) ? cnt[i] : 0;    // read BEFORE aliased write below
        s += c[k];
    }
    const int orig = s;
    sh[t] = s; __syncthreads();
    for (int off = 1; off < 256; off <<= 1) {
        const int v = (t >= off) ? sh[t - off] : 0;
        __syncthreads();
        sh[t] += v;
        __syncthreads();
    }
    int run = bsum[b] + sh[t] - orig;     // exclusive prefix of this thread
    #pragma unroll
    for (int k = 0; k < 4; ++k) {
        const int i = base + k;
        if (i < NN) { row_ptr[i] = run; cursor[i] = run; run += c[k]; }
    }
    if (b == 0 && t == 0) row_ptr[NN] = NE;
}

// Fused scatter: place src id AND edge_attr row directly into perm order.
__global__ __launch_bounds__(256)
void k_scatter2(const int* __restrict__ ei, const float* __restrict__ ea,
                int* __restrict__ cursor, int* __restrict__ src_perm,
                float* __restrict__ ea_perm)
{
    int e = blockIdx.x * 256 + threadIdx.x;
    const int stride = gridDim.x * 256;
    for (; e < NE; e += stride) {
        const int d = ei[NE + e];
        const int p = atomicAdd(&cursor[d], 1);
        src_perm[p] = ei[e];
        const float4* s = (const float4*)(ea + (size_t)e * ED);
        float4* t = (float4*)(ea_perm + (size_t)p * ED);
        t[0] = s[0]; t[1] = s[1]; t[2] = s[2]; t[3] = s[3];
    }
}

// One-shot: W[K,N] fp32 -> Wt[N,K] bf16 (transposed for the MFMA GEMM).
__global__ __launch_bounds__(256)
void k_wt(const float* __restrict__ W, bf16* __restrict__ Wt, int K, int N)
{
    const int i = blockIdx.x * 256 + threadIdx.x;
    if (i >= K * N) return;
    const int k = i / N, n = i % N;
    Wt[(size_t)n * K + k] = __float2bfloat16(W[i]);
}

// ===========================================================================
// Per-node aggregation v3: one wave per 128-channel slab (CPL=2), We column
// in VGPRs, chunk-of-8 src/gather batching for deep memory-level parallelism.
// agg[i] = x[i] + sum_{e: dst=i} relu(x[src_e] + ea_e@We + be), stored bf16.
// ===========================================================================
template<typename XT, int CIN>
__global__ __launch_bounds__(256)
void node_agg3(const XT* __restrict__ x, const float* __restrict__ ea_perm,
               const int* __restrict__ src_perm, const int* __restrict__ row_ptr,
               const float* __restrict__ We, const float* __restrict__ be,
               bf16* __restrict__ agg)
{
    constexpr int SLABS = CIN / 128;          // 1 (CIN=128) or 2 (CIN=256)
    const int lane = threadIdx.x & 63;
    const int gw   = blockIdx.x * 4 + (threadIdx.x >> 6);
    const int node = gw / SLABS;
    const int slab = gw % SLABS;
    if (node >= NN) return;
    const int c0 = slab * 128 + lane * 2;

    float w0[ED], w1[ED];
    #pragma unroll
    for (int k = 0; k < ED; ++k) {
        w0[k] = We[k * CIN + c0];
        w1[k] = We[k * CIN + c0 + 1];
    }
    const float b0 = be[c0], b1 = be[c0 + 1];

    const float2 xi = ld2f(&x[(size_t)node * CIN + c0]);
    float acc0 = xi.x, acc1 = xi.y;           // (1+eps)*x_i, eps=0

    const int e0 = row_ptr[node], e1 = row_ptr[node + 1];
    for (int base = e0; base < e1; base += 8) {
        // phase 1: batch 8 src ids (contiguous stream, wave-uniform rows)
        int ss[8];
        #pragma unroll
        for (int j = 0; j < 8; ++j) {
            int idx = base + j; if (idx >= e1) idx = e1 - 1;   // clamp: dup ok
            ss[j] = src_perm[idx];
        }
        // phase 2: batch 8 x-row gathers (8 independent loads in flight)
        float2 xv[8];
        #pragma unroll
        for (int j = 0; j < 8; ++j)
            xv[j] = ld2f(&x[(size_t)ss[j] * CIN + c0]);
        // phase 3: edge MLP (lane-replicated ea broadcast + register We)
        #pragma unroll
        for (int j = 0; j < 8; ++j) {
            if (base + j < e1) {
                const float* ep = ea_perm + (size_t)(base + j) * ED;
                float ev[ED];
                *(float4*)&ev[0]  = *(const float4*)(ep + 0);
                *(float4*)&ev[4]  = *(const float4*)(ep + 4);
                *(float4*)&ev[8]  = *(const float4*)(ep + 8);
                *(float4*)&ev[12] = *(const float4*)(ep + 12);
                float m0 = b0, m1 = b1;
                #pragma unroll
                for (int k = 0; k < ED; ++k) {
                    m0 = fmaf(ev[k], w0[k], m0);
                    m1 = fmaf(ev[k], w1[k], m1);
                }
                m0 += xv[j].x;
                m1 += xv[j].y;
                acc0 += fmaxf(m0, 0.f);
                acc1 += fmaxf(m1, 0.f);
            }
        }
    }

    union { ushort2 u; bf16 h[2]; } t;
    t.h[0] = __float2bfloat16(acc0);
    t.h[1] = __float2bfloat16(acc1);
    *(ushort2*)&agg[(size_t)node * CIN + c0] = t.u;
}

// ===========================================================================
// MFMA GEMM for conv layers: C[M,256] = relu(A[M,K] @ Wt[256,K]^T + bias)
// A bf16 row-major, Wt bf16 [N,K] (pre-transposed), C bf16, fp32 accumulate.
// 128x128 tile, BK=32, 256 threads = 4 waves (each 64x64), 16x16x32 MFMA.
// ===========================================================================
template<int K>
__global__ __launch_bounds__(256)
void gemm_mfma(const bf16* __restrict__ A, const bf16* __restrict__ Wt,
               const float* __restrict__ bias, bf16* __restrict__ C, int M)
{
    constexpr int LDT = 40;                 // padded LDS row stride (bf16)
    __shared__ short As[128 * LDT];
    __shared__ short Bs[128 * LDT];
    const int tid  = threadIdx.x;
    const int bm   = blockIdx.y * 128;
    const int bn   = blockIdx.x * 128;      // 0 or 128 (N = 256)
    const int lane = tid & 63;
    const int wave = tid >> 6;
    const int wr   = (wave >> 1) * 64;      // wave row offset in tile
    const int wc   = (wave & 1) * 64;       // wave col offset
    const int l15  = lane & 15;
    const int quad = lane >> 4;

    f32x4 acc[4][4];
    #pragma unroll
    for (int i = 0; i < 4; ++i)
        #pragma unroll
        for (int j = 0; j < 4; ++j)
            acc[i][j] = (f32x4){0.f, 0.f, 0.f, 0.f};

    for (int k0 = 0; k0 < K; k0 += 32) {
        #pragma unroll
        for (int c = tid; c < 512; c += 256) {
            const int row = c >> 2, part = c & 3;
            int ar = bm + row; if (ar >= M) ar = M - 1;   // clamp; rows discarded at store
            *(ulonglong2*)&As[row * LDT + part * 8] =
                *(const ulonglong2*)&A[(size_t)ar * K + k0 + part * 8];
            *(ulonglong2*)&Bs[row * LDT + part * 8] =
                *(const ulonglong2*)&Wt[(size_t)(bn + row) * K + k0 + part * 8];
        }
        __syncthreads();

        bf16x8 af[4], bfr[4];
        #pragma unroll
        for (int i = 0; i < 4; ++i) {
            af[i]  = *(const bf16x8*)&As[(wr + i * 16 + l15) * LDT + quad * 8];
            bfr[i] = *(const bf16x8*)&Bs[(wc + i * 16 + l15) * LDT + quad * 8];
        }
        #pragma unroll
        for (int mi = 0; mi < 4; ++mi)
            #pragma unroll
            for (int ni = 0; ni < 4; ++ni)
                acc[mi][ni] = __builtin_amdgcn_mfma_f32_16x16x32_bf16(
                                  af[mi], bfr[ni], acc[mi][ni], 0, 0, 0);
        __syncthreads();
    }

    // epilogue: D row = quad*4+reg, col = lane&15 (m89-verified C/D layout)
    float bv[4];
    #pragma unroll
    for (int ni = 0; ni < 4; ++ni)
        bv[ni] = bias[bn + wc + ni * 16 + l15];
    #pragma unroll
    for (int mi = 0; mi < 4; ++mi) {
        const int row0 = bm + wr + mi * 16 + quad * 4;
        #pragma unroll
        for (int r = 0; r < 4; ++r) {
            const int row = row0 + r;
            if (row < M) {
                #pragma unroll
                for (int ni = 0; ni < 4; ++ni) {
                    float v = acc[mi][ni][r] + bv[ni];
                    v = fmaxf(v, 0.f);
                    C[(size_t)row * 256 + bn + wc + ni * 16 + l15] = __float2bfloat16(v);
                }
            }
        }
    }
}

// ---------------------------------------------------------------------------
// fp32 GEMM (dense head only): C = (relu?)(A @ W + bias)
// ---------------------------------------------------------------------------
template<bool RELU, typename InT, typename OutT>
__global__ __launch_bounds__(256)
void gemm_rk(const InT* __restrict__ A, const float* __restrict__ W,
             const float* __restrict__ bias, OutT* __restrict__ C,
             int M, int N, int K)
{
    __shared__ float Asm[16][64];
    __shared__ float Wsm[16][64];
    const int bm = blockIdx.y * 64;
    const int bn = blockIdx.x * 64;
    const int tid = threadIdx.x;
    const int tx = tid & 15, ty = tid >> 4;
    const int ar = tid >> 2, ac = (tid & 3) * 4;
    const int wrr = tid >> 4, wcc = (tid & 15) * 4;

    float acc[4][4] = {};

    for (int k0 = 0; k0 < K; k0 += 16) {
        float4 av = make_float4(0.f, 0.f, 0.f, 0.f);
        if (bm + ar < M)
            av = ld4(A + (size_t)(bm + ar) * K + k0 + ac);
        Asm[ac + 0][ar] = av.x; Asm[ac + 1][ar] = av.y;
        Asm[ac + 2][ar] = av.z; Asm[ac + 3][ar] = av.w;

        float4 wv = make_float4(0.f, 0.f, 0.f, 0.f);
        if (bn + wcc < N)
            wv = *(const float4*)(W + (size_t)(k0 + wrr) * N + bn + wcc);
        *(float4*)&Wsm[wrr][wcc] = wv;
        __syncthreads();

        #pragma unroll
        for (int k = 0; k < 16; ++k) {
            const float4 a4 = *(const float4*)&Asm[k][ty * 4];
            const float4 b4 = *(const float4*)&Wsm[k][tx * 4];
            const float aa[4] = {a4.x, a4.y, a4.z, a4.w};
            const float bb[4] = {b4.x, b4.y, b4.z, b4.w};
            #pragma unroll
            for (int i = 0; i < 4; ++i)
                #pragma unroll
                for (int j = 0; j < 4; ++j)
                    acc[i][j] += aa[i] * bb[j];
        }
        __syncthreads();
    }

    float bvals[4];
    #pragma unroll
    for (int j = 0; j < 4; ++j) {
        const int col = bn + tx * 4 + j;
        bvals[j] = (col < N) ? bias[col] : 0.f;
    }
    #pragma unroll
    for (int i = 0; i < 4; ++i) {
        const int row = bm + ty * 4 + i;
        if (row >= M) continue;
        float v[4];
        #pragma unroll
        for (int j = 0; j < 4; ++j) {
            v[j] = acc[i][j] + bvals[j];
            if (RELU) v[j] = fmaxf(v[j], 0.f);
        }
        if (bn + tx * 4 + 3 < N) {
            st4(C + (size_t)row * N + bn + tx * 4, make_float4(v[0], v[1], v[2], v[3]));
        } else {
            #pragma unroll
            for (int j = 0; j < 4; ++j) {
                const int col = bn + tx * 4 + j;
                if (col < N) st1(C + (size_t)row * N + col, v[j]);
            }
        }
    }
}

// ---------------------------------------------------------------------------
// BatchNorm stats + normalize (bf16 H), fp32 accumulate.
// ---------------------------------------------------------------------------
template<typename InT>
__global__ __launch_bounds__(256)
void bn_stats(const InT* __restrict__ h, float* __restrict__ stats, int nodes)
{
    const int c = threadIdx.x;
    size_t n0 = (size_t)blockIdx.x * 128;
    size_t n1 = n0 + 128; if (n1 > (size_t)nodes) n1 = nodes;
    if (n0 >= (size_t)nodes) return;
    float s = 0.f, s2 = 0.f;
    for (size_t n = n0; n < n1; ++n) {
        const float v = ld1(&h[n * 256 + c]);
        s += v; s2 += v * v;
    }
    atomicAdd(&stats[c], s);
    atomicAdd(&stats[256 + c], s2);
}

template<typename T>
__global__ __launch_bounds__(256)
void bn_norm(T* __restrict__ h, const float* __restrict__ stats,
             const float* __restrict__ gamma, const float* __restrict__ beta, int n4)
{
    int i = blockIdx.x * 256 + threadIdx.x;
    const int stride = gridDim.x * 256;
    const float inv = 1.f / (float)NN;
    for (; i < n4; i += stride) {
        const int c = (i * 4) & 255;
        float4 v  = ld4(h + (size_t)i * 4);
        const float4 s  = *(const float4*)&stats[c];
        const float4 s2 = *(const float4*)&stats[256 + c];
        const float4 g  = *(const float4*)&gamma[c];
        const float4 b  = *(const float4*)&beta[c];
        float mu, sc;
        mu = s.x * inv; sc = rsqrtf(s2.x * inv - mu * mu + BN_EPS) * g.x; v.x = (v.x - mu) * sc + b.x;
        mu = s.y * inv; sc = rsqrtf(s2.y * inv - mu * mu + BN_EPS) * g.y; v.y = (v.y - mu) * sc + b.y;
        mu = s.z * inv; sc = rsqrtf(s2.z * inv - mu * mu + BN_EPS) * g.z; v.z = (v.z - mu) * sc + b.z;
        mu = s.w * inv; sc = rsqrtf(s2.w * inv - mu * mu + BN_EPS) * g.w; v.w = (v.w - mu) * sc + b.w;
        st4(h + (size_t)i * 4, v);
    }
}

// ---------------------------------------------------------------------------
// Mean-pool over sorted batch ids.
// ---------------------------------------------------------------------------
template<typename InT>
__global__ __launch_bounds__(256)
void pool_sum(const InT* __restrict__ h, const int* __restrict__ batch,
              float* __restrict__ sums, float* __restrict__ cnts)
{
    const int c = threadIdx.x;
    size_t n0 = (size_t)blockIdx.x * 128;
    size_t n1 = n0 + 128; if (n1 > (size_t)NN) n1 = NN;
    if (n0 >= (size_t)NN) return;
    int cur = batch[n0];
    float s = 0.f, cnt = 0.f;
    for (size_t n = n0; n < n1; ++n) {
        const int b = batch[n];
        if (b != cur) {
            atomicAdd(&sums[(size_t)cur * 256 + c], s);
            if (c == 0) atomicAdd(&cnts[cur], cnt);
            s = 0.f; cnt = 0.f; cur = b;
        }
        s += ld1(&h[n * 256 + c]);
        cnt += 1.f;
    }
    atomicAdd(&sums[(size_t)cur * 256 + c], s);
    if (c == 0) atomicAdd(&cnts[cur], cnt);
}

__global__ __launch_bounds__(256)
void pool_div(float* __restrict__ sums, const float* __restrict__ cnts)
{
    const int i = blockIdx.x * 256 + threadIdx.x;   // NG*256 threads exactly
    const int g = i >> 8;
    sums[i] = sums[i] / fmaxf(cnts[g], 1.f);
}

__global__ __launch_bounds__(256)
void head_out(const float* __restrict__ y, const float* __restrict__ Wo,
              const float* __restrict__ bo, float* __restrict__ out)
{
    const int g = blockIdx.x * 256 + threadIdx.x;
    if (g >= NG) return;
    float s = bo[0];
    #pragma unroll
    for (int k = 0; k < 32; ++k) s += y[g * 32 + k] * Wo[k];
    out[g] = s;
}

__global__ __launch_bounds__(256)
void diag_fill(float* __restrict__ out, int n, float v)
{
    const int i = blockIdx.x * 256 + threadIdx.x;
    if (i < n) out[i] = v;
}

// ---------------------------------------------------------------------------
extern "C" void kernel_launch(void* const* d_in, const int* in_sizes, int n_in,
                              void* d_out, int out_size, void* d_ws, size_t ws_size,
                              hipStream_t stream)
{
    const float* x    = (const float*)d_in[0];
    const int*   ei   = (const int*)d_in[1];
    const int*   batch= (const int*)d_in[2];
    const float* ea   = (const float*)d_in[3];
    const float* We[3] = {(const float*)d_in[4],  (const float*)d_in[10], (const float*)d_in[16]};
    const float* be[3] = {(const float*)d_in[5],  (const float*)d_in[11], (const float*)d_in[17]};
    const float* Wn[3] = {(const float*)d_in[6],  (const float*)d_in[12], (const float*)d_in[18]};
    const float* bnb[3]= {(const float*)d_in[7],  (const float*)d_in[13], (const float*)d_in[19]};
    const float* gm[3] = {(const float*)d_in[8],  (const float*)d_in[14], (const float*)d_in[20]};
    const float* bt[3] = {(const float*)d_in[9],  (const float*)d_in[15], (const float*)d_in[21]};
    const float* Wd0 = (const float*)d_in[22]; const float* bd0 = (const float*)d_in[23];
    const float* Wd1 = (const float*)d_in[24]; const float* bd1 = (const float*)d_in[25];
    const float* Wd2 = (const float*)d_in[26]; const float* bd2 = (const float*)d_in[27];
    const float* Wo  = (const float*)d_in[28]; const float* bo  = (const float*)d_in[29];
    float* out = (float*)d_out;
    float* ws  = (float*)d_ws;

    // ---- workspace layout (float offsets; 16B alignment kept) ----
    bf16*  H        = (bf16*)ws;                  // NN*256 bf16 = 25.6M fl
    bf16*  AGG      = (bf16*)(ws + 25600000);     // NN*256 bf16 = 25.6M fl
    float* st       = ws + 51200000;              // 512 fl
    bf16*  wt0      = (bf16*)(ws + 51200512);     // 128*256 bf16 = 16384 fl
    bf16*  wt1      = wt0 + 32768;                // 256*256 bf16 = 32768 fl
    bf16*  wt2      = wt1 + 65536;                // 256*256 bf16 = 32768 fl
    float* ea_perm  = ws + 51282432;              // NE*16 fp32 = 12.8M fl
    int*   src_perm = (int*)(ws + 64082432);      // NE
    int*   row_ptr  = src_perm + NE;              // NN+1
    int*   cursor   = row_ptr + (NN + 1);         // NN
    int*   bsum     = cursor + NN;                // SCAN_NBLK
    const size_t NEED = (size_t)(64082432 + NE + (NN + 1) + NN + SCAN_NBLK) * 4;

    if (ws_size < NEED) {
        diag_fill<<<(NG + 255) / 256, 256, 0, stream>>>(out, NG, (float)(ws_size >> 20));
        return;
    }

    // ---- one-time prep: CSR build + fused edge scatter, weight transpose ----
    hipMemsetAsync(row_ptr, 0, (size_t)(NN + 1) * 4, stream);
    k_hist<<<1024, 256, 0, stream>>>(ei, row_ptr);
    k_scan_block<<<SCAN_NBLK, 256, 0, stream>>>(row_ptr, bsum);
    k_scan_top<<<1, 256, 0, stream>>>(bsum, SCAN_NBLK);
    k_scan_emit<<<SCAN_NBLK, 256, 0, stream>>>(row_ptr, bsum, row_ptr, cursor);
    k_scatter2<<<1024, 256, 0, stream>>>(ei, ea, cursor, src_perm, ea_perm);
    k_wt<<<(128 * 256 + 255) / 256, 256, 0, stream>>>(Wn[0], wt0, 128, 256);
    k_wt<<<(256 * 256 + 255) / 256, 256, 0, stream>>>(Wn[1], wt1, 256, 256);
    k_wt<<<(256 * 256 + 255) / 256, 256, 0, stream>>>(Wn[2], wt2, 256, 256);

    const dim3 mfma_grid(2, (NN + 127) / 128);    // N=256 -> 2 col-blocks

    // ---- layer 0 (cin=128 -> 256), input x fp32, 1 wave/node ----
    node_agg3<float, 128><<<(NN + 3) / 4, 256, 0, stream>>>(x, ea_perm, src_perm, row_ptr, We[0], be[0], AGG);
    gemm_mfma<128><<<mfma_grid, 256, 0, stream>>>(AGG, wt0, bnb[0], H, NN);
    hipMemsetAsync(st, 0, 512 * 4, stream);
    bn_stats<bf16><<<(NN + 127) / 128, 256, 0, stream>>>(H, st, NN);
    bn_norm<bf16><<<2048, 256, 0, stream>>>(H, st, gm[0], bt[0], NN * 256 / 4);

    // ---- layers 1,2 (256 -> 256), input H bf16, 2 waves/node ----
    for (int l = 1; l < 3; ++l) {
        node_agg3<bf16, 256><<<(NN * 2 + 3) / 4, 256, 0, stream>>>(H, ea_perm, src_perm, row_ptr, We[l], be[l], AGG);
        gemm_mfma<256><<<mfma_grid, 256, 0, stream>>>(AGG, (l == 1) ? wt1 : wt2, bnb[l], H, NN);
        hipMemsetAsync(st, 0, 512 * 4, stream);
        bn_stats<bf16><<<(NN + 127) / 128, 256, 0, stream>>>(H, st, NN);
        bn_norm<bf16><<<2048, 256, 0, stream>>>(H, st, gm[l], bt[l], NN * 256 / 4);
    }

    // ---- head scratch overlays AGG (dead after last conv GEMM) ----
    float* poolb = (float*)AGG;           // NG*256 = 1,024,000 fl
    float* cnts  = poolb + 1024000;       // NG
    float* y1    = poolb + 1028000;       // NG*512
    float* y2    = poolb + 3076000;       // NG*128
    float* y3    = poolb + 3588000;       // NG*32

    hipMemsetAsync(poolb, 0, (size_t)NG * 256 * 4, stream);
    hipMemsetAsync(cnts, 0, (size_t)NG * 4, stream);
    pool_sum<bf16><<<(NN + 127) / 128, 256, 0, stream>>>(H, batch, poolb, cnts);
    pool_div<<<NG, 256, 0, stream>>>(poolb, cnts);

    // ---- dense head (fp32) ----
    gemm_rk<true, float, float><<<dim3(8, (NG + 63) / 64), 256, 0, stream>>>(poolb, Wd0, bd0, y1, NG, 512, 256);
    gemm_rk<true, float, float><<<dim3(2, (NG + 63) / 64), 256, 0, stream>>>(y1, Wd1, bd1, y2, NG, 128, 512);
    gemm_rk<true, float, float><<<dim3(1, (NG + 63) / 64), 256, 0, stream>>>(y2, Wd2, bd2, y3, NG, 32, 128);
    head_out<<<(NG + 255) / 256, 256, 0, stream>>>(y3, Wo, bo, out);
}